// Round 6
// baseline (886.402 us; speedup 1.0000x reference)
//
#include <hip/hip_runtime.h>

#define T_LEN 2048
#define HID   25
#define LOG2E 1.4426950408889634f

__device__ __forceinline__ float fast_rcp(float x) { return __builtin_amdgcn_rcpf(x); }
__device__ __forceinline__ float fast_exp2(float x) { return __builtin_amdgcn_exp2f(x); }

// One chain per 64-lane wave. Lower lane u owns gate rows i_u,g_u; upper lane
// 32+u owns f_u,o_u (50 fp32 weights/lane). Uniform code on both halves; one
// shfl_xor(32) hands i*tanh(g) to the upper half which owns c,h.
//
// KEY CHANGE (R6): h is wave-uniform (one chain per wave), so it is broadcast
// with 25 v_readlane_b32 into SGPRs instead of an LDS write->b128-read round
// trip. R5 was LDS-pipe-bound: ~95 cyc of DS occupancy per wave-step x 8
// waves/CU ~= 760 cyc/CU/step on the single per-CU LDS pipe (measured period
// 815). readlane moves that load onto the 4 per-CU VALU pipes.
//
// sigmoid/tanh in exp2 domain (weights pre-scaled by -log2e / +2log2e) ->
// v_exp_f32 + v_rcp_f32 only. Gate-dot summation order identical to R5
// (two accumulators, k=0..11 / 12..24) -> expect bit-identical output.

__global__ __launch_bounds__(256, 2) void lstm_fused(
    const float* __restrict__ x,        // [B, T, 1]
    const float* __restrict__ w_ih,     // [100, 1]
    const float* __restrict__ w_hh,     // [100, 25]
    const float* __restrict__ b_ih,     // [100]
    const float* __restrict__ b_hh,     // [100]
    const float* __restrict__ w_dense,  // [1, 25]
    const float* __restrict__ b_dense,  // [1]
    float* __restrict__ out)            // [B, T, 1]
{
    const int tid  = threadIdx.x;
    const int L    = tid & 63;           // lane in wave
    const int u    = L & 31;             // hidden-unit / t'-slot index
    const bool up  = L >= 32;            // upper half: f/o rows, owns c and h
    const int cl   = tid >> 6;           // wave (= chain) index in block, 0..3
    const int b    = blockIdx.x * 4 + cl;
    const bool act = u < HID;

    // Per-wave h history for batched y: 32 steps x 33 floats (stride 33 keeps
    // the strided reads in the y phase conflict-free).
    __shared__ float hist[4][32][33];

    const int rowA = up ? (HID + u)     : u;              // f-row : i-row
    const int rowB = up ? (3 * HID + u) : (2 * HID + u);  // o-row : g-row
    const float sclA = -LOG2E;                            // sigmoid gates
    const float sclB = up ? -LOG2E : 2.f * LOG2E;         // o: sigmoid, g: tanh

    // ---- 50 recurrent fp32 weights per lane, pre-scaled into exp2 domain ----
    float wAv[HID], wBv[HID];
#pragma unroll
    for (int k = 0; k < HID; ++k) {
        wAv[k] = act ? sclA * w_hh[rowA * HID + k] : 0.f;
        wBv[k] = act ? sclB * w_hh[rowB * HID + k] : 0.f;
    }
    const float bA  = act ? sclA * (b_ih[rowA] + b_hh[rowA]) : 0.f;
    const float bB  = act ? sclB * (b_ih[rowB] + b_hh[rowB]) : 0.f;
    const float wxA = act ? sclA * w_ih[rowA] : 0.f;
    const float wxB = act ? sclB * w_ih[rowB] : 0.f;
    const float bd  = b_dense[0];
    // tB = fmaf(-tmul, sB, 1): tanh(g) on lower half, exactly 1.0 on upper
    const float tmul = up ? 0.f : 2.f;

    // dense weights for the batched y phase: lower half sums u'=0..12,
    // upper half sums u'=13..24 (13th term zero)
    const int u0 = up ? 13 : 0;
    float wdv[13];
#pragma unroll
    for (int i = 0; i < 13; ++i) wdv[i] = (u0 + i < HID) ? w_dense[u0 + i] : 0.f;

    const float4* __restrict__ xp = (const float4*)(x + (size_t)b * T_LEN);
    float* __restrict__ orow = out + (size_t)b * T_LEN;

    // h state, wave-uniform (SGPR-resident): h0 = 0
    float sh[HID];
#pragma unroll
    for (int k = 0; k < HID; ++k) sh[k] = 0.f;

    float c = 0.f;        // real on upper half, bounded junk on lower
    float4 xcur = xp[0];

    for (int it = 0; it < T_LEN / 4; ++it) {
        const int nx = (it + 1 < T_LEN / 4) ? it + 1 : it;
        float4 xnext = xp[nx];  // issued ~1 iter (~4 steps) ahead of use
        float xs[4] = {xcur.x, xcur.y, xcur.z, xcur.w};

#pragma unroll
        for (int s = 0; s < 4; ++s) {
            const float xv = xs[s];
            const int t = 4 * it + s;

            // gate pre-activations, two accumulators per gate (chain 25->13),
            // summation order identical to R5 (passed at 1.95e-3)
            float aA0 = fmaf(xv, wxA, bA), aA1 = 0.f;
            float aB0 = fmaf(xv, wxB, bB), aB1 = 0.f;
#pragma unroll
            for (int k = 0; k < 12; ++k) {
                aA0 = fmaf(sh[k], wAv[k], aA0);
                aB0 = fmaf(sh[k], wBv[k], aB0);
            }
#pragma unroll
            for (int k = 12; k < HID; ++k) {
                aA1 = fmaf(sh[k], wAv[k], aA1);
                aB1 = fmaf(sh[k], wBv[k], aB1);
            }
            const float aA = aA0 + aA1;     // lower: i-preact, upper: f-preact
            const float aB = aB0 + aB1;     // lower: g-preact, upper: o-preact

            const float sA = fast_rcp(1.f + fast_exp2(aA));  // sig(i) / sig(f)
            const float sB = fast_rcp(1.f + fast_exp2(aB));  // g-aux  / sig(o)
            const float tB = fmaf(-tmul, sB, 1.f);           // tanh(g) / 1.0
            const float vv = sA * tB;                        // i*tanh(g) / sig(f)
            const float ov = __shfl_xor(vv, 32, 64);         // swap halves

            c = fmaf(vv, c, ov);             // upper: f*c + i*g   (lower: junk)
            const float tC = fmaf(-2.f, fast_rcp(1.f + fast_exp2(2.f * LOG2E * c)), 1.f);
            const float hn = sB * tC;        // upper: o*tanh(c)   (lower: junk)

            // h history for the batched y (only the 25 real lanes)
            if (up && act) hist[cl][t & 31][u] = hn;

            // broadcast h_t to all lanes: wave-uniform -> SGPRs, no LDS.
            // (fp32 bit-exact, same values the LDS round trip delivered)
            {
                const int hb = __builtin_bit_cast(int, hn);
#pragma unroll
                for (int k = 0; k < HID; ++k)
                    sh[k] = __builtin_bit_cast(float,
                              __builtin_amdgcn_readlane(hb, 32 + k));
            }

            // batched y: every 32 steps, lane L computes y[t0 + (L&31)] over
            // its half of the hidden units; shfl_xor(32) combines halves.
            if ((t & 31) == 31) {
                const float* hrow = &hist[cl][u][0];   // row for t' = t0 + u
                float ys = 0.f;
#pragma unroll
                for (int i = 0; i < 13; ++i)
                    ys = fmaf(hrow[u0 + i], wdv[i], ys);   // [25] slot reads junk*0
                ys += __shfl_xor(ys, 32, 64);
                if (!up) orow[(t & ~31) + u] = ys + bd;    // 128 B coalesced
            }
        }
        xcur = xnext;
    }
}

extern "C" void kernel_launch(void* const* d_in, const int* in_sizes, int n_in,
                              void* d_out, int out_size, void* d_ws, size_t ws_size,
                              hipStream_t stream) {
    const float* x       = (const float*)d_in[0];
    const float* w_ih    = (const float*)d_in[1];
    const float* w_hh    = (const float*)d_in[2];
    const float* b_ih    = (const float*)d_in[3];
    const float* b_hh    = (const float*)d_in[4];
    const float* w_dense = (const float*)d_in[5];
    const float* b_dense = (const float*)d_in[6];
    float* out = (float*)d_out;

    // 2048 chains, one per 64-lane wave: 512 blocks x 256 threads
    // -> 2 blocks/CU, 8 waves/CU = 2 waves/SIMD.
    lstm_fused<<<dim3(512), dim3(256), 0, stream>>>(x, w_ih, w_hh, b_ih, b_hh,
                                                    w_dense, b_dense, out);
}

// Round 8
// 620.148 us; speedup vs baseline: 1.4293x; 1.4293x over previous
//
#include <hip/hip_runtime.h>

#define T_LEN 2048
#define HID   25
#define LOG2E 1.4426950408889634f

// may_alias vector: the LDS h-row is written as scalar float and read as a
// 16B vector. Without may_alias, Clang TBAA treats <4 x float> and float as
// non-aliasing and may hoist the readback above the publish (the R3/R7
// failure). Belt and suspenders: asm memory fences pin the order too (the
// R4 kernel, the only fenced variant, is the only reordering-proof one that
// passed).
typedef float vf4 __attribute__((vector_size(16), may_alias));

__device__ __forceinline__ float fast_rcp(float x) { return __builtin_amdgcn_rcpf(x); }
__device__ __forceinline__ float fast_exp2(float x) { return __builtin_amdgcn_exp2f(x); }

// One chain per 32-lane half-wave; lane u owns ALL FOUR gate rows of hidden
// unit u (100 fp32 weights/lane). No cross-lane traffic in the recurrence
// except the h broadcast through LDS. amdgpu_waves_per_eu(1,1) un-caps the
// VGPR budget: R2-R6 showed VGPR_Count 48-80 against 130+ live floats ->
// loop-invariant weights demoted to AGPRs (no scratch traffic), one
// v_accvgpr_read per weight-use per step (~2x dynamic instructions).
// 1024 waves = 1 wave/SIMD chip-wide, so capping occupancy costs nothing.
// sigmoid/tanh in exp2 domain (weights pre-scaled by -log2e / +2log2e);
// per-gate fma order identical to the R5 kernel that passed at 1.953e-3.

__global__ __attribute__((amdgpu_flat_work_group_size(256, 256),
                          amdgpu_waves_per_eu(1, 1)))
void lstm_fused(
    const float* __restrict__ x,        // [B, T, 1]
    const float* __restrict__ w_ih,     // [100, 1]
    const float* __restrict__ w_hh,     // [100, 25]
    const float* __restrict__ b_ih,     // [100]
    const float* __restrict__ b_hh,     // [100]
    const float* __restrict__ w_dense,  // [1, 25]
    const float* __restrict__ b_dense,  // [1]
    float* __restrict__ out)            // [B, T, 1]
{
    const int tid  = threadIdx.x;
    const int u    = tid & 31;           // hidden unit / t'-slot owned by lane
    const int cb   = tid >> 5;           // chain index in block, 0..7
    const int b    = blockIdx.x * 8 + cb;
    const bool act = u < HID;

    // Broadcast row per chain: 32 floats. All 32 lanes publish (junk slots
    // 25..31 are finite and never read).
    __shared__ __align__(16) float hbuf[8][32];
    // h history for batched y: 32 steps x 33 floats (stride 33: bank of
    // hist[cb][u][i] = (u+i)%32 -> conflict-free for the lane=u read).
    __shared__ float hist[8][32][33];

    const float si = -LOG2E, sg = 2.f * LOG2E;

    // ---- 100 recurrent fp32 weights per lane, pre-scaled into exp2 domain ----
    float wI[HID], wF[HID], wG[HID], wO[HID];
#pragma unroll
    for (int k = 0; k < HID; ++k) {
        wI[k] = act ? si * w_hh[u * HID + k]             : 0.f;
        wF[k] = act ? si * w_hh[(HID + u) * HID + k]     : 0.f;
        wG[k] = act ? sg * w_hh[(2 * HID + u) * HID + k] : 0.f;
        wO[k] = act ? si * w_hh[(3 * HID + u) * HID + k] : 0.f;
    }
    const float bI  = act ? si * (b_ih[u] + b_hh[u]) : 0.f;
    const float bF  = act ? si * (b_ih[HID + u] + b_hh[HID + u]) : 0.f;
    const float bG  = act ? sg * (b_ih[2 * HID + u] + b_hh[2 * HID + u]) : 0.f;
    const float bO  = act ? si * (b_ih[3 * HID + u] + b_hh[3 * HID + u]) : 0.f;
    const float wxI = act ? si * w_ih[u] : 0.f;
    const float wxF = act ? si * w_ih[HID + u] : 0.f;
    const float wxG = act ? sg * w_ih[2 * HID + u] : 0.f;
    const float wxO = act ? si * w_ih[3 * HID + u] : 0.f;
    const float bd  = b_dense[0];

    // dense weights (wave-uniform loads -> SGPRs)
    float wdv[HID];
#pragma unroll
    for (int i = 0; i < HID; ++i) wdv[i] = w_dense[i];

    // h0 = 0
    hbuf[cb][u] = 0.f;

    float* hwr = &hbuf[cb][u];
    const vf4* r4 = (const vf4*)&hbuf[cb][0];
    const float* hbF = &hbuf[cb][0];

    const float4* __restrict__ xp = (const float4*)(x + (size_t)b * T_LEN);
    float* __restrict__ orow = out + (size_t)b * T_LEN;

    float hv[HID];
#pragma unroll
    for (int k = 0; k < HID; ++k) hv[k] = 0.f;

    float c = 0.f;
    float4 xcur = xp[0];

    for (int it = 0; it < T_LEN / 4; ++it) {
        const int nx = (it + 1 < T_LEN / 4) ? it + 1 : it;
        float4 xnext = xp[nx];  // issued ~4 steps ahead of use
        float xs[4] = {xcur.x, xcur.y, xcur.z, xcur.w};

#pragma unroll
        for (int s = 0; s < 4; ++s) {
            const float xv = xs[s];
            const int t = 4 * it + s;

            // four gate pre-activations, two accumulators each (chain 25->13);
            // per-gate fma order identical to R5 (passed at 1.953e-3)
            float aI0 = fmaf(xv, wxI, bI), aI1 = 0.f;
            float aF0 = fmaf(xv, wxF, bF), aF1 = 0.f;
            float aG0 = fmaf(xv, wxG, bG), aG1 = 0.f;
            float aO0 = fmaf(xv, wxO, bO), aO1 = 0.f;
#pragma unroll
            for (int k = 0; k < 12; ++k) {
                const float h = hv[k];
                aI0 = fmaf(h, wI[k], aI0);
                aF0 = fmaf(h, wF[k], aF0);
                aG0 = fmaf(h, wG[k], aG0);
                aO0 = fmaf(h, wO[k], aO0);
            }
#pragma unroll
            for (int k = 12; k < HID; ++k) {
                const float h = hv[k];
                aI1 = fmaf(h, wI[k], aI1);
                aF1 = fmaf(h, wF[k], aF1);
                aG1 = fmaf(h, wG[k], aG1);
                aO1 = fmaf(h, wO[k], aO1);
            }
            const float aI = aI0 + aI1;
            const float aF = aF0 + aF1;
            const float aG = aG0 + aG1;
            const float aO = aO0 + aO1;

            const float sI = fast_rcp(1.f + fast_exp2(aI));          // sig(i)
            const float sF = fast_rcp(1.f + fast_exp2(aF));          // sig(f)
            const float sO = fast_rcp(1.f + fast_exp2(aO));          // sig(o)
            const float tG = fmaf(-2.f, fast_rcp(1.f + fast_exp2(aG)), 1.f); // tanh(g)

            c = fmaf(sF, c, sI * tG);
            const float tC = fmaf(-2.f, fast_rcp(1.f + fast_exp2(2.f * LOG2E * c)), 1.f);
            const float hn = sO * tC;

            // ---- ordered publish -> readback (the R3/R7 failure was this
            // pair getting reordered; fences are compile-time only) ----
            *hwr = hn;
            hist[cb][t & 31][u] = hn;
            __asm__ __volatile__("" ::: "memory");
            {
                vf4 a0 = r4[0], a1 = r4[1], a2 = r4[2];
                vf4 a3 = r4[3], a4 = r4[4], a5 = r4[5];
                hv[0]  = a0[0]; hv[1]  = a0[1]; hv[2]  = a0[2]; hv[3]  = a0[3];
                hv[4]  = a1[0]; hv[5]  = a1[1]; hv[6]  = a1[2]; hv[7]  = a1[3];
                hv[8]  = a2[0]; hv[9]  = a2[1]; hv[10] = a2[2]; hv[11] = a2[3];
                hv[12] = a3[0]; hv[13] = a3[1]; hv[14] = a3[2]; hv[15] = a3[3];
                hv[16] = a4[0]; hv[17] = a4[1]; hv[18] = a4[2]; hv[19] = a4[3];
                hv[20] = a5[0]; hv[21] = a5[1]; hv[22] = a5[2]; hv[23] = a5[3];
                hv[24] = hbF[24];
            }
            __asm__ __volatile__("" ::: "memory");

            // batched y: every 32 steps lane u computes y[t0+u] (full 25-sum;
            // hist reads conflict-free by stride-33), all 32 lanes store.
            if ((t & 31) == 31) {
                const float* hrow = &hist[cb][u][0];   // row for t' = t0 + u
                float ys = 0.f;
#pragma unroll
                for (int i = 0; i < HID; ++i)
                    ys = fmaf(hrow[i], wdv[i], ys);
                orow[(t & ~31) + u] = ys + bd;         // 128 B coalesced
            }
        }
        xcur = xnext;
    }
}

extern "C" void kernel_launch(void* const* d_in, const int* in_sizes, int n_in,
                              void* d_out, int out_size, void* d_ws, size_t ws_size,
                              hipStream_t stream) {
    const float* x       = (const float*)d_in[0];
    const float* w_ih    = (const float*)d_in[1];
    const float* w_hh    = (const float*)d_in[2];
    const float* b_ih    = (const float*)d_in[3];
    const float* b_hh    = (const float*)d_in[4];
    const float* w_dense = (const float*)d_in[5];
    const float* b_dense = (const float*)d_in[6];
    float* out = (float*)d_out;

    // 2048 chains, one per 32-lane half-wave: 256 blocks x 256 threads
    // -> 1024 waves = 1 wave/SIMD chip-wide, 4 waves/CU.
    lstm_fused<<<dim3(256), dim3(256), 0, stream>>>(x, w_ih, w_hh, b_ih, b_hh,
                                                    w_dense, b_dense, out);
}